// Round 12
// baseline (371.398 us; speedup 1.0000x reference)
//
#include <hip/hip_runtime.h>

typedef unsigned short u16;
typedef unsigned int u32;
typedef __attribute__((ext_vector_type(8))) short bfrag;   // 8 bf16
typedef __attribute__((ext_vector_type(4))) float ffrag;   // 4 fp32 acc

__device__ __forceinline__ float lrelu(float x) { return x >= 0.f ? x : 0.01f * x; }
__device__ __forceinline__ float eluf(float x)  { return x > 0.f ? x : expm1f(x); }
__device__ __forceinline__ u16 f2bf(float f) {            // RNE (wprep only)
    u32 x = __float_as_uint(f);
    return (u16)((x + 0x7fffu + ((x >> 16) & 1u)) >> 16);
}
__device__ __forceinline__ u16 f2bt(float f) {            // truncate (internal)
    return (u16)(__float_as_uint(f) >> 16);
}
__device__ __forceinline__ float bf2f(u16 u) {
    return __uint_as_float(((u32)u) << 16);
}

// sparsemax over 16 elements (Martins & Astudillo), exact ksup-count semantics
__device__ void sparsemax16(const float* z, float* out) {
    float zs[16];
    for (int i = 0; i < 16; ++i) zs[i] = z[i];
    for (int i = 1; i < 16; ++i) {
        float key = zs[i]; int j = i - 1;
        while (j >= 0 && zs[j] < key) { zs[j + 1] = zs[j]; --j; }
        zs[j + 1] = key;
    }
    float cum[16];
    cum[0] = zs[0];
    for (int i = 1; i < 16; ++i) cum[i] = cum[i - 1] + zs[i];
    int ksup = 0;
    for (int k = 1; k <= 16; ++k)
        if (1.0f + (float)k * zs[k - 1] > cum[k - 1]) ksup++;
    if (ksup < 1) ksup = 1;
    float tau = (cum[ksup - 1] - 1.0f) / (float)ksup;
    for (int i = 0; i < 16; ++i) out[i] = fmaxf(z[i] - tau, 0.0f);
}

// ---- device-scope grid barrier (monotonic counter, all 256 blocks resident)
__device__ __forceinline__ void grid_arrive(u32* ctr) {
    __syncthreads();
    if (threadIdx.x == 0)
        __hip_atomic_fetch_add(ctr, 1u, __ATOMIC_ACQ_REL, __HIP_MEMORY_SCOPE_AGENT);
}
__device__ __forceinline__ void grid_wait(u32* ctr, u32 target) {
    if (threadIdx.x == 0) {
        u32 v;
        do {
            __builtin_amdgcn_s_sleep(2);
            v = __hip_atomic_load(ctr, __ATOMIC_ACQUIRE, __HIP_MEMORY_SCOPE_AGENT);
        } while (v < target);
    }
    __syncthreads();
}

// ---- weight pre-pack into B-fragment order (bf16) + barrier-counter zero ----
__global__ __launch_bounds__(256) void k_wprep(
    const float* __restrict__ w2, const float* __restrict__ w3,
    const float* __restrict__ Wq, const float* __restrict__ Wk,
    const float* __restrict__ Wv,
    u16* __restrict__ wpk2, u16* __restrict__ wpk3, u16* __restrict__ wqkv,
    u32* __restrict__ bar)
{
    int i = blockIdx.x * 256 + threadIdx.x;
    if (i == 0) *bar = 0;
    if (i < 131072) {
        int j = i & 7, L = (i >> 3) & 63, kc = (i >> 9) & 7, nt = (i >> 12) & 3, f = i >> 14;
        int co = nt * 16 + (L & 15);
        int ci = ((L >> 4) << 3) + j;
        wpk2[i] = f2bf(w2[(((size_t)f * 64 + co) * 32 + ci) * 8 + kc]);
    } else if (i < 131072 + 524288) {
        int i2 = i - 131072;
        int j = i2 & 7, L = (i2 >> 3) & 63, kc = (i2 >> 9) & 15, nt = (i2 >> 13) & 7, f = i2 >> 16;
        int co = nt * 16 + (L & 15);
        int ci = ((kc & 1) << 5) + ((L >> 4) << 3) + j;
        wpk3[i2] = f2bf(w3[(((size_t)f * 128 + co) * 64 + ci) * 8 + (kc >> 1)]);
    } else if (i < 131072 + 524288 + 49152) {
        int j2 = i - 655360;
        int proj = j2 >> 14, idx = j2 & 16383;
        int jj = idx & 7, L = (idx >> 3) & 63, kc = (idx >> 9) & 3, nt = idx >> 11;
        int n = nt * 16 + (L & 15);
        int k = kc * 32 + ((L >> 4) << 3) + jj;
        const float* W = proj == 0 ? Wq : (proj == 1 ? Wk : Wv);
        wqkv[j2] = f2bf(W[k * 128 + n]);
    }
}

// ===== fused CNN (both passes): conv1 fp32 -> conv2/conv3 bf16 MFMA ==========
#define S1T_STRIDE 40
#define S2T_STRIDE 72
#define RB2_STRIDE 68
#define RB3_STRIDE 140
#define RB_OFF 6336
#define SMEM_U16 (RB_OFF + 67 * RB3_STRIDE)

__global__ __launch_bounds__(256) void k_cnn(
    const float* __restrict__ xs, const float* __restrict__ xt,
    const float* __restrict__ w1, const float* __restrict__ g1, const float* __restrict__ b1,
    const float* __restrict__ m1, const float* __restrict__ v1,
    const float* __restrict__ g2, const float* __restrict__ b2,
    const float* __restrict__ m2, const float* __restrict__ v2,
    const float* __restrict__ g3, const float* __restrict__ b3,
    const float* __restrict__ m3, const float* __restrict__ v3,
    const u16* __restrict__ wpk2, const u16* __restrict__ wpk3,
    float* __restrict__ rep)
{
    __shared__ __align__(16) u16 smem[SMEM_U16];
    float* xin = (float*)(smem + RB_OFF);      // 264 floats (region B head)

    int tid = threadIdx.x, blk = blockIdx.x;
    int pass = blk >> 11, f = (blk >> 8) & 7, n = blk & 255;
    int bb = n >> 4, ss = n & 15;
    int lane = tid & 63, w = tid >> 6;
    const float* x = pass ? xt : xs;
    float* rep_p = rep + (size_t)pass * 262144;

    {
        u32* z = (u32*)smem;
        for (int i = tid; i < 80; i += 256) z[i] = 0;          // s1T rows 0..3
        for (int i = tid; i < 360; i += 256) z[2660 + i] = 0;  // s1T rows 133..150
        if (tid < 4) { xin[tid] = 0.f; xin[260 + tid] = 0.f; }
        const float* xr = x + (((size_t)bb * 8 + f) * 16 + ss) * 256;
        for (int i = tid; i < 256; i += 256) xin[i + 4] = xr[i];
    }
    __syncthreads();

    // ---- conv1 fp32 (1->32, 256 -> conv 257 -> pool 129) ----
    if (tid < 208) {
        int cc = tid & 7, jc = tid >> 3;
        int co0 = cc * 4, j0 = jc * 5;
        float wr[4][8];
        for (int c = 0; c < 4; ++c) {
            const float4* q = reinterpret_cast<const float4*>(w1 + ((size_t)f * 32 + co0 + c) * 8);
            float4 a = q[0], bq = q[1];
            wr[c][0] = a.x; wr[c][1] = a.y; wr[c][2] = a.z; wr[c][3] = a.w;
            wr[c][4] = bq.x; wr[c][5] = bq.y; wr[c][6] = bq.z; wr[c][7] = bq.w;
        }
        int px[10];
        for (int i = 0; i < 10; ++i) {
            int p = 2 * j0 - 1 + i;
            px[i] = p < 0 ? 0 : (p > 256 ? 256 : p);
        }
        float acc[4][10];
        for (int c = 0; c < 4; ++c) for (int i = 0; i < 10; ++i) acc[c][i] = 0.f;
        for (int k = 0; k < 8; ++k) {
            float xv[10];
            for (int i = 0; i < 10; ++i) xv[i] = xin[px[i] + k];
            for (int c = 0; c < 4; ++c)
                for (int i = 0; i < 10; ++i) acc[c][i] += wr[c][k] * xv[i];
        }
        for (int c = 0; c < 4; ++c) {
            int co = co0 + c;
            float sc = g1[f * 32 + co] * rsqrtf(v1[f * 32 + co] + 1e-5f);
            float sh = b1[f * 32 + co] - m1[f * 32 + co] * sc;
            for (int jj = 0; jj < 5; ++jj) {
                int j = j0 + jj;
                if (j < 129) {
                    float a0 = fmaxf(acc[c][2 * jj] * sc + sh, 0.f);
                    float a1 = fmaxf(acc[c][2 * jj + 1] * sc + sh, 0.f);
                    smem[(j + 4) * S1T_STRIDE + co] = f2bt(fmaxf(a0, a1));
                }
            }
        }
    }
    __syncthreads();

    // ---- conv2 MFMA (M=130 pos, N=64 co, K=256) -> region B raw ----
    {
        int nt = w;
        bfrag B2[8];
        const bfrag* gB = reinterpret_cast<const bfrag*>(wpk2);
        for (int kc = 0; kc < 8; ++kc)
            B2[kc] = gB[(((size_t)f * 4 + nt) * 8 + kc) * 64 + lane];
        int co = nt * 16 + (lane & 15);
        float sc = g2[f * 64 + co] * rsqrtf(v2[f * 64 + co] + 1e-5f);
        float sh = b2[f * 64 + co] - m2[f * 64 + co] * sc;
        int arow = lane & 15, ci0 = (lane >> 4) << 3;
        for (int mt = 0; mt < 9; ++mt) {
            ffrag C = {0.f, 0.f, 0.f, 0.f};
            int rb = mt * 16 + arow;
            for (int kc = 0; kc < 8; ++kc) {
                bfrag A = *reinterpret_cast<const bfrag*>(&smem[(rb + kc) * S1T_STRIDE + ci0]);
                C = __builtin_amdgcn_mfma_f32_16x16x32_bf16(A, B2[kc], C, 0, 0, 0);
            }
            int p0 = mt * 16 + ((lane >> 4) << 2);
            for (int r = 0; r < 4; ++r) {
                int p = p0 + r;
                if (p < 130)
                    smem[RB_OFF + p * RB2_STRIDE + co] = f2bt(fmaxf(C[r] * sc + sh, 0.f));
            }
        }
    }
    __syncthreads();

    // ---- pool conv2 -> s2T (region A) + zero s2T pad rows ----
    {
        u32* z = (u32*)smem;
        for (int i = tid; i < 144; i += 256) z[i] = 0;
        for (int i = tid; i < 612; i += 256) z[2520 + i] = 0;
    }
    for (int e = tid; e < 66 * 64; e += 256) {
        int j = e >> 6, ci = e & 63;
        float vmax;
        if (j == 0) {
            vmax = bf2f(smem[RB_OFF + 0 * RB2_STRIDE + ci]);
        } else if (j == 65) {
            vmax = bf2f(smem[RB_OFF + 129 * RB2_STRIDE + ci]);
        } else {
            float a0 = bf2f(smem[RB_OFF + (2 * j - 1) * RB2_STRIDE + ci]);
            float a1 = bf2f(smem[RB_OFF + (2 * j) * RB2_STRIDE + ci]);
            vmax = fmaxf(a0, a1);
        }
        smem[(j + 4) * S2T_STRIDE + ci] = f2bt(vmax);
    }
    __syncthreads();

    // ---- conv3 MFMA (M=67 pos, N=128 co, K=512) -> region B raw ----
    for (int t = 0; t < 2; ++t) {
        int nt = w * 2 + t;
        bfrag B3[16];
        const bfrag* gB = reinterpret_cast<const bfrag*>(wpk3);
        for (int kc = 0; kc < 16; ++kc)
            B3[kc] = gB[(((size_t)f * 8 + nt) * 16 + kc) * 64 + lane];
        int co = nt * 16 + (lane & 15);
        float sc = g3[f * 128 + co] * rsqrtf(v3[f * 128 + co] + 1e-5f);
        float sh = b3[f * 128 + co] - m3[f * 128 + co] * sc;
        int arow = lane & 15, q8 = (lane >> 4) << 3;
        for (int mt = 0; mt < 5; ++mt) {
            ffrag C = {0.f, 0.f, 0.f, 0.f};
            int rb = mt * 16 + arow;
            for (int kc = 0; kc < 16; ++kc) {
                int row = rb + (kc >> 1);
                int ci0 = ((kc & 1) << 5) + q8;
                bfrag A = *reinterpret_cast<const bfrag*>(&smem[row * S2T_STRIDE + ci0]);
                C = __builtin_amdgcn_mfma_f32_16x16x32_bf16(A, B3[kc], C, 0, 0, 0);
            }
            int p0 = mt * 16 + ((lane >> 4) << 2);
            for (int r = 0; r < 4; ++r) {
                int p = p0 + r;
                if (p < 67)
                    smem[RB_OFF + p * RB3_STRIDE + co] = f2bt(fmaxf(C[r] * sc + sh, 0.f));
            }
        }
    }
    __syncthreads();

    // ---- pool conv3 + mean -> rep ----
    if (tid < 128) {
        int co = tid;
        float sum = bf2f(smem[RB_OFF + 0 * RB3_STRIDE + co]);
        for (int j = 1; j < 34; ++j) {
            float a0 = bf2f(smem[RB_OFF + (2 * j - 1) * RB3_STRIDE + co]);
            float a1 = bf2f(smem[RB_OFF + (2 * j) * RB3_STRIDE + co]);
            sum += fmaxf(a0, a1);
        }
        rep_p[(((size_t)f * 256) + n) * 128 + co] = sum * (1.0f / 34.0f);
    }
}

// ===== fused post: attn1 | attn2 | head1 | tail with grid barriers ==========
// 256 blocks x 256 threads; all stages bit-identical to the R11 kernels.
__global__ __launch_bounds__(256) void k_post(
    const float* __restrict__ rep, const u16* __restrict__ wqkv,
    const float* __restrict__ bq, const float* __restrict__ bk,
    const float* __restrict__ bv,
    float* __restrict__ Zn, float* __restrict__ rninv,
    float* __restrict__ iaw, float* __restrict__ ibw,
    const float* __restrict__ gC, const float* __restrict__ bC,
    const float* __restrict__ mC, const float* __restrict__ vC,
    float* __restrict__ featbn,
    const float* __restrict__ W1, const float* __restrict__ b1d,
    const float* __restrict__ g2c, const float* __restrict__ bb2,
    const float* __restrict__ mm2, const float* __restrict__ vv2,
    float* __restrict__ h2ws,
    const float* __restrict__ W2, const float* __restrict__ b2d,
    const int* __restrict__ sy, float* __restrict__ dout,
    u32* __restrict__ bar)
{
    __shared__ __align__(16) unsigned char sbuf[67600];
    int tid = threadIdx.x, blk = blockIdx.x;
    int lane = tid & 63, w = tid >> 6;

    // =================== stage A: attn1 (blk = pass*128 + f*16 + b) =========
    {
        u16* repbf = (u16*)sbuf;                       // 16*136 u16
        float* KmL = (float*)(sbuf + 4352);
        float* ZL = KmL + 128;
        float* awL = ZL + 128;
        float* scoresL = awL + 16;
        float* r2L = scoresL + 16;
        float* spart = r2L + 16;                       // [w][q][r] 64
        float* redL = spart + 64;

        int pass = blk >> 7, f = (blk >> 4) & 7, b = blk & 15;
        const float* rp = rep + (size_t)pass * 262144 + ((size_t)f * 256 + b * 16) * 128;
        float* Zn_p = Zn + (size_t)pass * 16384;
        float* rninv_p = rninv + (size_t)pass * 2048;
        float* iaw_p = iaw + (size_t)pass * 2048;

        {
            int s = tid >> 4, i = tid & 15, h0 = i * 8;
            const float4* q4 = reinterpret_cast<const float4*>(rp + s * 128 + h0);
            float4 a = q4[0], c = q4[1];
            float p2 = a.x*a.x + a.y*a.y + a.z*a.z + a.w*a.w
                     + c.x*c.x + c.y*c.y + c.z*c.z + c.w*c.w;
            bfrag pk;
            pk[0] = (short)f2bt(a.x); pk[1] = (short)f2bt(a.y);
            pk[2] = (short)f2bt(a.z); pk[3] = (short)f2bt(a.w);
            pk[4] = (short)f2bt(c.x); pk[5] = (short)f2bt(c.y);
            pk[6] = (short)f2bt(c.z); pk[7] = (short)f2bt(c.w);
            *reinterpret_cast<bfrag*>(&repbf[s * 136 + h0]) = pk;
            p2 += __shfl_xor(p2, 1); p2 += __shfl_xor(p2, 2);
            p2 += __shfl_xor(p2, 4); p2 += __shfl_xor(p2, 8);
            if (i == 0) r2L[s] = p2;
        }
        __syncthreads();

        int arow = lane & 15, q = lane >> 4;
        bfrag A[4];
        for (int kc = 0; kc < 4; ++kc)
            A[kc] = *reinterpret_cast<const bfrag*>(&repbf[arow * 136 + kc * 32 + q * 8]);

        float qv[2][4], vvv[2][4];
        int colv[2];
        const bfrag* BB = reinterpret_cast<const bfrag*>(wqkv);
        for (int t = 0; t < 2; ++t) {
            int nt = w * 2 + t;
            ffrag cq = {0.f,0.f,0.f,0.f}, ck = {0.f,0.f,0.f,0.f}, cv = {0.f,0.f,0.f,0.f};
            for (int kc = 0; kc < 4; ++kc) {
                int fi = (nt * 4 + kc) * 64 + lane;
                bfrag Bq = BB[fi];
                bfrag Bk = BB[2048 + fi];
                bfrag Bv = BB[4096 + fi];
                cq = __builtin_amdgcn_mfma_f32_16x16x32_bf16(A[kc], Bq, cq, 0, 0, 0);
                ck = __builtin_amdgcn_mfma_f32_16x16x32_bf16(A[kc], Bk, ck, 0, 0, 0);
                cv = __builtin_amdgcn_mfma_f32_16x16x32_bf16(A[kc], Bv, cv, 0, 0, 0);
            }
            int col = nt * 16 + arow;
            colv[t] = col;
            float bqc = bq[col], bkc = bk[col], bvc = bv[col];
            float kpt = 0.f;
            for (int r = 0; r < 4; ++r) {
                qv[t][r] = eluf(cq[r] + bqc);
                vvv[t][r] = lrelu(cv[r] + bvc);
                kpt += lrelu(ck[r] + bkc);
            }
            kpt += __shfl_xor(kpt, 16);
            kpt += __shfl_xor(kpt, 32);
            if (q == 0) KmL[col] = kpt * (1.f / 16.f);
        }
        __syncthreads();

        {
            float km0 = KmL[colv[0]], km1 = KmL[colv[1]];
            float ps[4];
            for (int r = 0; r < 4; ++r) {
                float v = qv[0][r] * km0 + qv[1][r] * km1;
                v += __shfl_xor(v, 1); v += __shfl_xor(v, 2);
                v += __shfl_xor(v, 4); v += __shfl_xor(v, 8);
                ps[r] = v;
            }
            if (arow == 0)
                for (int r = 0; r < 4; ++r) spart[w * 16 + q * 4 + r] = ps[r];
        }
        __syncthreads();
        if (tid < 16) {
            int qq = tid >> 2, rr = tid & 3;
            float sc = spart[0 * 16 + qq * 4 + rr] + spart[1 * 16 + qq * 4 + rr]
                     + spart[2 * 16 + qq * 4 + rr] + spart[3 * 16 + qq * 4 + rr];
            scoresL[tid] = sc * 0.08838834764831845f;   // 1/sqrt(128)
            rninv_p[f * 256 + b * 16 + tid] = 1.f / fmaxf(sqrtf(r2L[tid]), 1e-12f);
        }
        __syncthreads();
        if (tid == 0) sparsemax16(scoresL, awL);
        __syncthreads();
        if (tid < 16) iaw_p[f * 256 + b * 16 + tid] = awL[tid];

        for (int t = 0; t < 2; ++t) {
            float zp = 0.f;
            for (int r = 0; r < 4; ++r) zp += awL[q * 4 + r] * vvv[t][r];
            zp += __shfl_xor(zp, 16);
            zp += __shfl_xor(zp, 32);
            if (q == 0) ZL[colv[t]] = zp;
        }
        __syncthreads();
        if (tid < 128) {
            float z = ZL[tid];
            float v = z * z;
            v += __shfl_xor(v, 1); v += __shfl_xor(v, 2); v += __shfl_xor(v, 4);
            v += __shfl_xor(v, 8); v += __shfl_xor(v, 16); v += __shfl_xor(v, 32);
            if (lane == 0) redL[w] = v;
        }
        __syncthreads();
        if (tid == 0) redL[2] = 1.f / fmaxf(sqrtf(redL[0] + redL[1]), 1e-12f);
        __syncthreads();
        if (tid < 128)
            Zn_p[((size_t)f * 16 + b) * 128 + tid] = ZL[tid] * redL[2];
    }
    grid_arrive(bar);
    grid_wait(bar, 256);

    // =================== stage B: attn2 (blk = pass*128 + b*8 + i) ==========
    {
        float* repL = (float*)sbuf;                    // 16384 floats
        float* ZiL = (float*)(sbuf + 65536);
        float* scores = ZiL + 128;
        float* UL = scores + 128;
        float* awLf = UL + 128;                        // [f][s] 128
        float* redB = awLf + 128;

        int pass = blk >> 7, b = (blk >> 3) & 15, i = blk & 7;
        const float* rep_p = rep + (size_t)pass * 262144;

        for (int f = 0; f < 8; ++f) {
            const float4* src = reinterpret_cast<const float4*>(
                rep_p + ((size_t)f * 256 + b * 16) * 128);
            float4* dst = reinterpret_cast<float4*>(repL + f * 2048);
            for (int t = tid; t < 512; t += 256) dst[t] = src[t];
        }
        if (tid < 128) ZiL[tid] = Zn[(size_t)pass * 16384 + ((size_t)i * 16 + b) * 128 + tid];
        __syncthreads();

        if (tid < 128) {
            int f = tid >> 4, s = tid & 15;
            const float* rr = repL + tid * 128;
            float a = 0.f;
            for (int h = 0; h < 128; ++h) a += ZiL[h] * rr[h];
            scores[tid] = a * rninv[(size_t)pass * 2048 + f * 256 + b * 16 + s];
        }
        __syncthreads();
        if (tid < 8) {
            float aw[16];
            sparsemax16(&scores[tid * 16], aw);
            for (int s = 0; s < 16; ++s) awLf[tid * 16 + s] = aw[s];
        }
        __syncthreads();
        if (tid < 128) {
            int f = tid >> 4, s = tid & 15;
            ibw[(size_t)pass * 16384 + (((size_t)i * 8 + f) * 16 + b) * 16 + s] = awLf[f * 16 + s];
        }
        if (pass == 0) {
            if (tid < 128) {
                int h = tid;
                float u = 0.f;
                for (int f = 0; f < 8; ++f) {
                    const float* rr = repL + f * 2048 + h;
                    const float* aa = awLf + f * 16;
                    for (int s = 0; s < 16; ++s) u += aa[s] * rr[s * 128];
                }
                UL[h] = u * 0.125f;
            }
            __syncthreads();
            if (tid < 128) {
                float v = ZiL[tid] * ZiL[tid] + UL[tid] * UL[tid];
                v += __shfl_xor(v, 1); v += __shfl_xor(v, 2); v += __shfl_xor(v, 4);
                v += __shfl_xor(v, 8); v += __shfl_xor(v, 16); v += __shfl_xor(v, 32);
                if (lane == 0) redB[w] = v;
            }
            __syncthreads();
            {
                float inv = 1.f / fmaxf(sqrtf(redB[0] + redB[1]), 1e-12f);
                int d = tid;
                int e = i * 256 + d;
                float val = (d < 128 ? ZiL[d] : UL[d - 128]) * inv;
                float scv = gC[e] * rsqrtf(vC[e] + 1e-5f);
                featbn[b * 2048 + e] = (val - mC[e]) * scv + bC[e];
            }
        }
    }
    grid_arrive(bar);
    grid_wait(bar, 512);

    // =================== stage C: head1 (blk = b*16 + cc) ===================
    {
        float* featL = (float*)sbuf;                   // 2048
        float* part = featL + 2048;                    // [ks][ci] 1024

        int b = blk >> 4, cc = blk & 15;
        {
            const float4* src = reinterpret_cast<const float4*>(featbn + b * 2048);
            float4* dst = reinterpret_cast<float4*>(featL);
            for (int i = tid; i < 512; i += 256) dst[i] = src[i];
        }
        __syncthreads();
        int ks = tid >> 3, cg = tid & 7;
        int col0 = cc * 32 + cg * 4;
        float4 acc = {0.f, 0.f, 0.f, 0.f};
        const float* fl = featL + ks * 64;
        for (int c = 0; c < 64; ++c) {
            int k = ks * 64 + c;
            float4 wv = *reinterpret_cast<const float4*>(W1 + (size_t)k * 512 + col0);
            float fv = fl[c];
            acc.x += fv * wv.x; acc.y += fv * wv.y;
            acc.z += fv * wv.z; acc.w += fv * wv.w;
        }
        part[ks * 32 + cg * 4 + 0] = acc.x;
        part[ks * 32 + cg * 4 + 1] = acc.y;
        part[ks * 32 + cg * 4 + 2] = acc.z;
        part[ks * 32 + cg * 4 + 3] = acc.w;
        __syncthreads();
        if (tid < 32) {
            int colw = cc * 32 + tid;
            float s = b1d[colw];
            for (int k2 = 0; k2 < 32; ++k2) s += part[k2 * 32 + tid];
            float scv = g2c[colw] * rsqrtf(vv2[colw] + 1e-5f);
            float val = (s - mm2[colw]) * scv + bb2[colw];
            h2ws[b * 512 + colw] = lrelu(val);
        }
    }
    grid_arrive(bar);
    if (blk != 0) return;
    grid_wait(bar, 768);

    // =================== stage D: tail (block 0 only) =======================
    {
        float* h2L = (float*)sbuf;                     // 8192
        float* lgL = h2L + 8192;                       // 160
        float* ypL = lgL + 160;                        // 160
        float* sA = ypL + 160;                         // 8
        float* sB = sA + 8;                            // 8
        const float* sa = iaw;
        const float* ta = iaw + 2048;
        const float* sbp = ibw;
        const float* tbp = ibw + 16384;

        for (int i = tid; i < 8192; i += 256) h2L[i] = h2ws[i];
        if (tid < 8) { sA[tid] = 0.f; sB[tid] = 0.f; }
        __syncthreads();
        if (tid < 160) {
            int b = tid / 10, j = tid - b * 10;
            float a = b2d[j];
            const float* h = h2L + b * 512;
            for (int c = 0; c < 512; ++c) a += h[c] * W2[c * 10 + j];
            lgL[tid] = a;
        }
        __syncthreads();
        if (tid < 16) {
            int b = tid;
            float mx = lgL[b * 10];
            for (int j = 1; j < 10; ++j) mx = fmaxf(mx, lgL[b * 10 + j]);
            float sum = 0.f, ex[10];
            for (int j = 0; j < 10; ++j) { ex[j] = expf(lgL[b * 10 + j] - mx); sum += ex[j]; }
            for (int j = 0; j < 10; ++j) {
                float p = ex[j] / sum;
                ypL[b * 10 + j] = p;
                dout[b * 10 + j] = p;
            }
        }
        __syncthreads();
        if (tid < 128) {
            int f = tid >> 4, s = tid & 15;
            float d = 0.f;
            for (int b = 0; b < 16; ++b) d += sa[f * 256 + b * 16 + s] - ta[f * 256 + b * 16 + s];
            d *= (1.f / 16.f);
            atomicAdd(&sA[f], d * d);
        }
        for (int e = tid; e < 1024; e += 256) {
            int i = e >> 7, f = (e >> 4) & 7, s = e & 15;
            float d = 0.f;
            int base = ((i * 8 + f) * 16) * 16 + s;
            for (int b = 0; b < 16; ++b) d += sbp[base + b * 16] - tbp[base + b * 16];
            d *= (1.f / 16.f);
            atomicAdd(&sB[i], d * d);
        }
        __syncthreads();
        if (tid == 0) {
            float la = 0.f, lb = 0.f;
            for (int f = 0; f < 8; ++f) la += sqrtf(sA[f]);
            for (int i = 0; i < 8; ++i) lb += sqrtf(sB[i]);
            la *= 0.1f / 8.f;
            lb *= 0.1f / 8.f;
            float ce = 0.f;
            for (int b = 0; b < 16; ++b) {
                const float* y = ypL + b * 10;
                float mx = y[0];
                for (int j = 1; j < 10; ++j) mx = fmaxf(mx, y[j]);
                float sum = 0.f;
                for (int j = 0; j < 10; ++j) sum += expf(y[j] - mx);
                float lse = mx + logf(sum);
                ce += lse - y[sy[b]];
            }
            ce *= (1.f / 16.f);
            dout[160] = ce + la + lb;
        }
    }
}

extern "C" void kernel_launch(void* const* d_in, const int* in_sizes, int n_in,
                              void* d_out, int out_size, void* d_ws, size_t ws_size,
                              hipStream_t stream) {
    (void)in_sizes; (void)n_in; (void)out_size; (void)ws_size;
    const float* src_x = (const float*)d_in[0];
    const int*   src_y = (const int*)d_in[1];
    const float* tgt_x = (const float*)d_in[2];
    const float *cw1 = (const float*)d_in[3], *bn1g = (const float*)d_in[4],
                *bn1b = (const float*)d_in[5], *bn1m = (const float*)d_in[6],
                *bn1v = (const float*)d_in[7];
    const float *cw2 = (const float*)d_in[8], *bn2g = (const float*)d_in[9],
                *bn2b = (const float*)d_in[10], *bn2m = (const float*)d_in[11],
                *bn2v = (const float*)d_in[12];
    const float *cw3 = (const float*)d_in[13], *bn3g = (const float*)d_in[14],
                *bn3b = (const float*)d_in[15], *bn3m = (const float*)d_in[16],
                *bn3v = (const float*)d_in[17];
    const float *Wq = (const float*)d_in[18], *bq = (const float*)d_in[19],
                *Wk = (const float*)d_in[20], *bk = (const float*)d_in[21],
                *Wv = (const float*)d_in[22], *bv = (const float*)d_in[23];
    const float *bc1g = (const float*)d_in[24], *bc1b = (const float*)d_in[25],
                *bc1m = (const float*)d_in[26], *bc1v = (const float*)d_in[27];
    const float *W1 = (const float*)d_in[28], *b1 = (const float*)d_in[29];
    const float *bc2g = (const float*)d_in[30], *bc2b = (const float*)d_in[31],
                *bc2m = (const float*)d_in[32], *bc2v = (const float*)d_in[33];
    const float *W2 = (const float*)d_in[34], *b2 = (const float*)d_in[35];

    float* ws = (float*)d_ws;
    size_t o = 0;
    float* rep    = ws + o; o += (size_t)2 * 262144;   // [pass][f,n,h]
    float* Zn     = ws + o; o += (size_t)2 * 16384;
    float* rninv  = ws + o; o += (size_t)2 * 2048;
    float* ia     = ws + o; o += (size_t)2 * 2048;
    float* ib     = ws + o; o += (size_t)2 * 16384;
    float* featbn = ws + o; o += (size_t)16 * 2048;
    float* h2ws   = ws + o; o += (size_t)16 * 512;
    u16* wpk2 = (u16*)(ws + o); o += 65536;            // 131072 u16
    u16* wpk3 = (u16*)(ws + o); o += 262144;           // 524288 u16
    u16* wqkv = (u16*)(ws + o); o += 24576;            // 49152 u16
    u32* bar  = (u32*)(ws + o); o += 16;

    k_wprep<<<2752, 256, 0, stream>>>(cw2, cw3, Wq, Wk, Wv, wpk2, wpk3, wqkv, bar);
    k_cnn<<<4096, 256, 0, stream>>>(src_x, tgt_x,
        cw1, bn1g, bn1b, bn1m, bn1v,
        bn2g, bn2b, bn2m, bn2v,
        bn3g, bn3b, bn3m, bn3v,
        wpk2, wpk3, rep);
    k_post<<<256, 256, 0, stream>>>(rep, wqkv, bq, bk, bv, Zn, rninv, ia, ib,
                                    bc1g, bc1b, bc1m, bc1v, featbn,
                                    W1, b1, bc2g, bc2b, bc2m, bc2v, h2ws,
                                    W2, b2, src_y, (float*)d_out, bar);
}

// Round 13
// 311.390 us; speedup vs baseline: 1.1927x; 1.1927x over previous
//
#include <hip/hip_runtime.h>

typedef unsigned short u16;
typedef unsigned int u32;
typedef __attribute__((ext_vector_type(8))) short bfrag;   // 8 bf16
typedef __attribute__((ext_vector_type(4))) float ffrag;   // 4 fp32 acc

__device__ __forceinline__ float lrelu(float x) { return x >= 0.f ? x : 0.01f * x; }
__device__ __forceinline__ float eluf(float x)  { return x > 0.f ? x : expm1f(x); }
__device__ __forceinline__ u16 f2bf(float f) {            // RNE (wprep only)
    u32 x = __float_as_uint(f);
    return (u16)((x + 0x7fffu + ((x >> 16) & 1u)) >> 16);
}
__device__ __forceinline__ u16 f2bt(float f) {            // truncate (internal)
    return (u16)(__float_as_uint(f) >> 16);
}
__device__ __forceinline__ float bf2f(u16 u) {
    return __uint_as_float(((u32)u) << 16);
}

// sparsemax over 16 elements (Martins & Astudillo), exact ksup-count semantics
__device__ void sparsemax16(const float* z, float* out) {
    float zs[16];
    for (int i = 0; i < 16; ++i) zs[i] = z[i];
    for (int i = 1; i < 16; ++i) {
        float key = zs[i]; int j = i - 1;
        while (j >= 0 && zs[j] < key) { zs[j + 1] = zs[j]; --j; }
        zs[j + 1] = key;
    }
    float cum[16];
    cum[0] = zs[0];
    for (int i = 1; i < 16; ++i) cum[i] = cum[i - 1] + zs[i];
    int ksup = 0;
    for (int k = 1; k <= 16; ++k)
        if (1.0f + (float)k * zs[k - 1] > cum[k - 1]) ksup++;
    if (ksup < 1) ksup = 1;
    float tau = (cum[ksup - 1] - 1.0f) / (float)ksup;
    for (int i = 0; i < 16; ++i) out[i] = fmaxf(z[i] - tau, 0.0f);
}

// ---- weight pre-pack into B-fragment order (bf16), 4 elems/thread ----------
__global__ __launch_bounds__(256) void k_wprep(
    const float* __restrict__ w2, const float* __restrict__ w3,
    const float* __restrict__ Wq, const float* __restrict__ Wk,
    const float* __restrict__ Wv,
    u16* __restrict__ wpk2, u16* __restrict__ wpk3, u16* __restrict__ wqkv)
{
    int i0 = (blockIdx.x * 256 + threadIdx.x) * 4;
    for (int t = 0; t < 4; ++t) {
        int i = i0 + t;
        if (i < 131072) {
            int j = i & 7, L = (i >> 3) & 63, kc = (i >> 9) & 7, nt = (i >> 12) & 3, f = i >> 14;
            int co = nt * 16 + (L & 15);
            int ci = ((L >> 4) << 3) + j;
            wpk2[i] = f2bf(w2[(((size_t)f * 64 + co) * 32 + ci) * 8 + kc]);
        } else if (i < 131072 + 524288) {
            int i2 = i - 131072;
            int j = i2 & 7, L = (i2 >> 3) & 63, kc = (i2 >> 9) & 15, nt = (i2 >> 13) & 7, f = i2 >> 16;
            int co = nt * 16 + (L & 15);
            int ci = ((kc & 1) << 5) + ((L >> 4) << 3) + j;
            wpk3[i2] = f2bf(w3[(((size_t)f * 128 + co) * 64 + ci) * 8 + (kc >> 1)]);
        } else if (i < 131072 + 524288 + 49152) {
            int j2 = i - 655360;
            int proj = j2 >> 14, idx = j2 & 16383;
            int jj = idx & 7, L = (idx >> 3) & 63, kc = (idx >> 9) & 3, nt = idx >> 11;
            int n = nt * 16 + (L & 15);
            int k = kc * 32 + ((L >> 4) << 3) + jj;
            const float* W = proj == 0 ? Wq : (proj == 1 ? Wk : Wv);
            wqkv[j2] = f2bf(W[k * 128 + n]);
        }
    }
}

// ===== fused CNN (both passes): conv1 fp32 -> conv2/conv3 bf16 MFMA ==========
#define S1T_STRIDE 40
#define S2T_STRIDE 72
#define RB2_STRIDE 68
#define RB3_STRIDE 140
#define RB_OFF 6336
#define SMEM_U16 (RB_OFF + 67 * RB3_STRIDE)

__global__ __launch_bounds__(256) void k_cnn(
    const float* __restrict__ xs, const float* __restrict__ xt,
    const float* __restrict__ w1, const float* __restrict__ g1, const float* __restrict__ b1,
    const float* __restrict__ m1, const float* __restrict__ v1,
    const float* __restrict__ g2, const float* __restrict__ b2,
    const float* __restrict__ m2, const float* __restrict__ v2,
    const float* __restrict__ g3, const float* __restrict__ b3,
    const float* __restrict__ m3, const float* __restrict__ v3,
    const u16* __restrict__ wpk2, const u16* __restrict__ wpk3,
    float* __restrict__ rep)
{
    __shared__ __align__(16) u16 smem[SMEM_U16];
    float* xin = (float*)(smem + RB_OFF);      // 264 floats (region B head)

    int tid = threadIdx.x, blk = blockIdx.x;
    int pass = blk >> 11, f = (blk >> 8) & 7, n = blk & 255;
    int bb = n >> 4, ss = n & 15;
    int lane = tid & 63, w = tid >> 6;
    const float* x = pass ? xt : xs;
    float* rep_p = rep + (size_t)pass * 262144;

    // ---- B2 fragments preloaded early: no LDS dependency, overlaps conv1 ---
    bfrag B2[8];
    {
        const bfrag* gB = reinterpret_cast<const bfrag*>(wpk2);
        for (int kc = 0; kc < 8; ++kc)
            B2[kc] = gB[(((size_t)f * 4 + w) * 8 + kc) * 64 + lane];
    }

    {
        u32* z = (u32*)smem;
        for (int i = tid; i < 80; i += 256) z[i] = 0;          // s1T rows 0..3
        for (int i = tid; i < 360; i += 256) z[2660 + i] = 0;  // s1T rows 133..150
        if (tid < 4) { xin[tid] = 0.f; xin[260 + tid] = 0.f; }
        const float* xr = x + (((size_t)bb * 8 + f) * 16 + ss) * 256;
        for (int i = tid; i < 256; i += 256) xin[i + 4] = xr[i];
    }
    __syncthreads();

    // ---- conv1 fp32 (1->32, 256 -> conv 257 -> pool 129) ----
    if (tid < 208) {
        int cc = tid & 7, jc = tid >> 3;
        int co0 = cc * 4, j0 = jc * 5;
        float wr[4][8];
        for (int c = 0; c < 4; ++c) {
            const float4* q = reinterpret_cast<const float4*>(w1 + ((size_t)f * 32 + co0 + c) * 8);
            float4 a = q[0], bq = q[1];
            wr[c][0] = a.x; wr[c][1] = a.y; wr[c][2] = a.z; wr[c][3] = a.w;
            wr[c][4] = bq.x; wr[c][5] = bq.y; wr[c][6] = bq.z; wr[c][7] = bq.w;
        }
        int px[10];
        for (int i = 0; i < 10; ++i) {
            int p = 2 * j0 - 1 + i;
            px[i] = p < 0 ? 0 : (p > 256 ? 256 : p);
        }
        float acc[4][10];
        for (int c = 0; c < 4; ++c) for (int i = 0; i < 10; ++i) acc[c][i] = 0.f;
        for (int k = 0; k < 8; ++k) {
            float xv[10];
            for (int i = 0; i < 10; ++i) xv[i] = xin[px[i] + k];
            for (int c = 0; c < 4; ++c)
                for (int i = 0; i < 10; ++i) acc[c][i] += wr[c][k] * xv[i];
        }
        for (int c = 0; c < 4; ++c) {
            int co = co0 + c;
            float sc = g1[f * 32 + co] * rsqrtf(v1[f * 32 + co] + 1e-5f);
            float sh = b1[f * 32 + co] - m1[f * 32 + co] * sc;
            for (int jj = 0; jj < 5; ++jj) {
                int j = j0 + jj;
                if (j < 129) {
                    float a0 = fmaxf(acc[c][2 * jj] * sc + sh, 0.f);
                    float a1 = fmaxf(acc[c][2 * jj + 1] * sc + sh, 0.f);
                    smem[(j + 4) * S1T_STRIDE + co] = f2bt(fmaxf(a0, a1));
                }
            }
        }
    }
    __syncthreads();

    // ---- conv2 MFMA (M=130 pos, N=64 co, K=256) -> region B raw ----
    {
        int nt = w;
        int co = nt * 16 + (lane & 15);
        float sc = g2[f * 64 + co] * rsqrtf(v2[f * 64 + co] + 1e-5f);
        float sh = b2[f * 64 + co] - m2[f * 64 + co] * sc;
        int arow = lane & 15, ci0 = (lane >> 4) << 3;
        for (int mt = 0; mt < 9; ++mt) {
            ffrag C = {0.f, 0.f, 0.f, 0.f};
            int rb = mt * 16 + arow;
            for (int kc = 0; kc < 8; ++kc) {
                bfrag A = *reinterpret_cast<const bfrag*>(&smem[(rb + kc) * S1T_STRIDE + ci0]);
                C = __builtin_amdgcn_mfma_f32_16x16x32_bf16(A, B2[kc], C, 0, 0, 0);
            }
            int p0 = mt * 16 + ((lane >> 4) << 2);
            for (int r = 0; r < 4; ++r) {
                int p = p0 + r;
                if (p < 130)
                    smem[RB_OFF + p * RB2_STRIDE + co] = f2bt(fmaxf(C[r] * sc + sh, 0.f));
            }
        }
    }
    __syncthreads();

    // ---- pool conv2 -> s2T (region A) + zero s2T pad rows ----
    {
        u32* z = (u32*)smem;
        for (int i = tid; i < 144; i += 256) z[i] = 0;
        for (int i = tid; i < 612; i += 256) z[2520 + i] = 0;
    }
    for (int e = tid; e < 66 * 64; e += 256) {
        int j = e >> 6, ci = e & 63;
        float vmax;
        if (j == 0) {
            vmax = bf2f(smem[RB_OFF + 0 * RB2_STRIDE + ci]);
        } else if (j == 65) {
            vmax = bf2f(smem[RB_OFF + 129 * RB2_STRIDE + ci]);
        } else {
            float a0 = bf2f(smem[RB_OFF + (2 * j - 1) * RB2_STRIDE + ci]);
            float a1 = bf2f(smem[RB_OFF + (2 * j) * RB2_STRIDE + ci]);
            vmax = fmaxf(a0, a1);
        }
        smem[(j + 4) * S2T_STRIDE + ci] = f2bt(vmax);
    }
    __syncthreads();

    // ---- conv3 MFMA (M=67 pos, N=128 co, K=512) -> region B raw ----
    for (int t = 0; t < 2; ++t) {
        int nt = w * 2 + t;
        bfrag B3[16];
        const bfrag* gB = reinterpret_cast<const bfrag*>(wpk3);
        for (int kc = 0; kc < 16; ++kc)
            B3[kc] = gB[(((size_t)f * 8 + nt) * 16 + kc) * 64 + lane];
        int co = nt * 16 + (lane & 15);
        float sc = g3[f * 128 + co] * rsqrtf(v3[f * 128 + co] + 1e-5f);
        float sh = b3[f * 128 + co] - m3[f * 128 + co] * sc;
        int arow = lane & 15, q8 = (lane >> 4) << 3;
        for (int mt = 0; mt < 5; ++mt) {
            ffrag C = {0.f, 0.f, 0.f, 0.f};
            int rb = mt * 16 + arow;
            for (int kc = 0; kc < 16; ++kc) {
                int row = rb + (kc >> 1);
                int ci0 = ((kc & 1) << 5) + q8;
                bfrag A = *reinterpret_cast<const bfrag*>(&smem[row * S2T_STRIDE + ci0]);
                C = __builtin_amdgcn_mfma_f32_16x16x32_bf16(A, B3[kc], C, 0, 0, 0);
            }
            int p0 = mt * 16 + ((lane >> 4) << 2);
            for (int r = 0; r < 4; ++r) {
                int p = p0 + r;
                if (p < 67)
                    smem[RB_OFF + p * RB3_STRIDE + co] = f2bt(fmaxf(C[r] * sc + sh, 0.f));
            }
        }
    }
    __syncthreads();

    // ---- pool conv3 + mean -> rep ----
    if (tid < 128) {
        int co = tid;
        float sum = bf2f(smem[RB_OFF + 0 * RB3_STRIDE + co]);
        for (int j = 1; j < 34; ++j) {
            float a0 = bf2f(smem[RB_OFF + (2 * j - 1) * RB3_STRIDE + co]);
            float a1 = bf2f(smem[RB_OFF + (2 * j) * RB3_STRIDE + co]);
            sum += fmaxf(a0, a1);
        }
        rep_p[(((size_t)f * 256) + n) * 128 + co] = sum * (1.0f / 34.0f);
    }
}

// ---- attn1 (MFMA): QKV proj + Km + scores + sparsemax + Z + rninv ----------
__global__ __launch_bounds__(256) void k_attn1(
    const float* __restrict__ rep, const u16* __restrict__ wqkv,
    const float* __restrict__ bq, const float* __restrict__ bk,
    const float* __restrict__ bv,
    float* __restrict__ Zn, float* __restrict__ rninv, float* __restrict__ iaw)
{
    __shared__ __align__(16) u16 repbf[16 * 136];
    __shared__ float KmL[128], ZL[128], awL[16], scoresL[16], r2L[16];
    __shared__ float spart[4][4][4];
    __shared__ float redL[4];
    int tid = threadIdx.x;
    int pass = blockIdx.x >> 7, f = (blockIdx.x >> 4) & 7, b = blockIdx.x & 15;
    const float* rp = rep + (size_t)pass * 262144 + ((size_t)f * 256 + b * 16) * 128;
    float* Zn_p = Zn + (size_t)pass * 16384;
    float* rninv_p = rninv + (size_t)pass * 2048;
    float* iaw_p = iaw + (size_t)pass * 2048;

    {
        int s = tid >> 4, i = tid & 15, h0 = i * 8;
        const float4* q4 = reinterpret_cast<const float4*>(rp + s * 128 + h0);
        float4 a = q4[0], c = q4[1];
        float p2 = a.x*a.x + a.y*a.y + a.z*a.z + a.w*a.w
                 + c.x*c.x + c.y*c.y + c.z*c.z + c.w*c.w;
        bfrag pk;
        pk[0] = (short)f2bt(a.x); pk[1] = (short)f2bt(a.y);
        pk[2] = (short)f2bt(a.z); pk[3] = (short)f2bt(a.w);
        pk[4] = (short)f2bt(c.x); pk[5] = (short)f2bt(c.y);
        pk[6] = (short)f2bt(c.z); pk[7] = (short)f2bt(c.w);
        *reinterpret_cast<bfrag*>(&repbf[s * 136 + h0]) = pk;
        p2 += __shfl_xor(p2, 1); p2 += __shfl_xor(p2, 2);
        p2 += __shfl_xor(p2, 4); p2 += __shfl_xor(p2, 8);
        if (i == 0) r2L[s] = p2;
    }
    __syncthreads();

    int lane = tid & 63, w = tid >> 6, arow = lane & 15, q = lane >> 4;
    bfrag A[4];
    for (int kc = 0; kc < 4; ++kc)
        A[kc] = *reinterpret_cast<const bfrag*>(&repbf[arow * 136 + kc * 32 + q * 8]);

    float qv[2][4], vvv[2][4];
    int colv[2];
    const bfrag* BB = reinterpret_cast<const bfrag*>(wqkv);
    for (int t = 0; t < 2; ++t) {
        int nt = w * 2 + t;
        ffrag cq = {0.f,0.f,0.f,0.f}, ck = {0.f,0.f,0.f,0.f}, cv = {0.f,0.f,0.f,0.f};
        for (int kc = 0; kc < 4; ++kc) {
            int fi = (nt * 4 + kc) * 64 + lane;
            bfrag Bq = BB[fi];
            bfrag Bk = BB[2048 + fi];
            bfrag Bv = BB[4096 + fi];
            cq = __builtin_amdgcn_mfma_f32_16x16x32_bf16(A[kc], Bq, cq, 0, 0, 0);
            ck = __builtin_amdgcn_mfma_f32_16x16x32_bf16(A[kc], Bk, ck, 0, 0, 0);
            cv = __builtin_amdgcn_mfma_f32_16x16x32_bf16(A[kc], Bv, cv, 0, 0, 0);
        }
        int col = nt * 16 + arow;
        colv[t] = col;
        float bqc = bq[col], bkc = bk[col], bvc = bv[col];
        float kpt = 0.f;
        for (int r = 0; r < 4; ++r) {
            qv[t][r] = eluf(cq[r] + bqc);
            vvv[t][r] = lrelu(cv[r] + bvc);
            kpt += lrelu(ck[r] + bkc);
        }
        kpt += __shfl_xor(kpt, 16);
        kpt += __shfl_xor(kpt, 32);
        if (q == 0) KmL[col] = kpt * (1.f / 16.f);
    }
    __syncthreads();

    {
        float km0 = KmL[colv[0]], km1 = KmL[colv[1]];
        float ps[4];
        for (int r = 0; r < 4; ++r) {
            float v = qv[0][r] * km0 + qv[1][r] * km1;
            v += __shfl_xor(v, 1); v += __shfl_xor(v, 2);
            v += __shfl_xor(v, 4); v += __shfl_xor(v, 8);
            ps[r] = v;
        }
        if (arow == 0)
            for (int r = 0; r < 4; ++r) spart[w][q][r] = ps[r];
    }
    __syncthreads();
    if (tid < 16) {
        int qq = tid >> 2, rr = tid & 3;
        float sc = spart[0][qq][rr] + spart[1][qq][rr] + spart[2][qq][rr] + spart[3][qq][rr];
        scoresL[tid] = sc * 0.08838834764831845f;   // 1/sqrt(128)
        rninv_p[f * 256 + b * 16 + tid] = 1.f / fmaxf(sqrtf(r2L[tid]), 1e-12f);
    }
    __syncthreads();
    if (tid == 0) sparsemax16(scoresL, awL);
    __syncthreads();
    if (tid < 16) iaw_p[f * 256 + b * 16 + tid] = awL[tid];

    for (int t = 0; t < 2; ++t) {
        float zp = 0.f;
        for (int r = 0; r < 4; ++r) zp += awL[q * 4 + r] * vvv[t][r];
        zp += __shfl_xor(zp, 16);
        zp += __shfl_xor(zp, 32);
        if (q == 0) ZL[colv[t]] = zp;
    }
    __syncthreads();
    if (tid < 128) {
        float z = ZL[tid];
        float v = z * z;
        v += __shfl_xor(v, 1); v += __shfl_xor(v, 2); v += __shfl_xor(v, 4);
        v += __shfl_xor(v, 8); v += __shfl_xor(v, 16); v += __shfl_xor(v, 32);
        if (lane == 0) redL[w] = v;
    }
    __syncthreads();
    if (tid == 0) redL[2] = 1.f / fmaxf(sqrtf(redL[0] + redL[1]), 1e-12f);
    __syncthreads();
    if (tid < 128)
        Zn_p[((size_t)f * 16 + b) * 128 + tid] = ZL[tid] * redL[2];
}

// ---- attn2 (split): one block per (pass,b,i) -------------------------------
__global__ __launch_bounds__(256) void k_attn2(
    const float* __restrict__ rep, const float* __restrict__ Zn,
    const float* __restrict__ rninv, float* __restrict__ ibw,
    const float* __restrict__ g, const float* __restrict__ bb,
    const float* __restrict__ mm, const float* __restrict__ vv,
    float* __restrict__ featbn)
{
    __shared__ float repL[16384];    // [f][s][h]
    __shared__ float ZiL[128], scores[128], UL[128];
    __shared__ float awLf[8][16];
    __shared__ float redL[2];
    int tid = threadIdx.x, blk = blockIdx.x;
    int pass = blk >> 7, b = (blk >> 3) & 15, i = blk & 7;
    const float* rep_p = rep + (size_t)pass * 262144;

    for (int f = 0; f < 8; ++f) {
        const float4* src = reinterpret_cast<const float4*>(
            rep_p + ((size_t)f * 256 + b * 16) * 128);
        float4* dst = reinterpret_cast<float4*>(repL + f * 2048);
        for (int t = tid; t < 512; t += 256) dst[t] = src[t];
    }
    if (tid < 128) ZiL[tid] = Zn[(size_t)pass * 16384 + ((size_t)i * 16 + b) * 128 + tid];
    __syncthreads();

    if (tid < 128) {
        int f = tid >> 4, s = tid & 15;
        const float* rr = repL + tid * 128;
        float a = 0.f;
        for (int h = 0; h < 128; ++h) a += ZiL[h] * rr[h];
        scores[tid] = a * rninv[(size_t)pass * 2048 + f * 256 + b * 16 + s];
    }
    __syncthreads();
    if (tid < 8) {
        float aw[16];
        sparsemax16(&scores[tid * 16], aw);
        for (int s = 0; s < 16; ++s) awLf[tid][s] = aw[s];
    }
    __syncthreads();
    if (tid < 128) {
        int f = tid >> 4, s = tid & 15;
        ibw[(size_t)pass * 16384 + (((size_t)i * 8 + f) * 16 + b) * 16 + s] = awLf[f][s];
    }
    if (pass == 0) {
        if (tid < 128) {
            int h = tid;
            float u = 0.f;
            for (int f = 0; f < 8; ++f) {
                const float* rr = repL + f * 2048 + h;
                const float* aa = awLf[f];
                for (int s = 0; s < 16; ++s) u += aa[s] * rr[s * 128];
            }
            UL[h] = u * 0.125f;
        }
        __syncthreads();
        if (tid < 128) {
            int lane = tid & 63, w = tid >> 6;
            float v = ZiL[tid] * ZiL[tid] + UL[tid] * UL[tid];
            v += __shfl_xor(v, 1); v += __shfl_xor(v, 2); v += __shfl_xor(v, 4);
            v += __shfl_xor(v, 8); v += __shfl_xor(v, 16); v += __shfl_xor(v, 32);
            if (lane == 0) redL[w] = v;
        }
        __syncthreads();
        if (tid < 256) {
            float inv = 1.f / fmaxf(sqrtf(redL[0] + redL[1]), 1e-12f);
            int d = tid;
            int e = i * 256 + d;
            float val = (d < 128 ? ZiL[d] : UL[d - 128]) * inv;
            float scv = g[e] * rsqrtf(vv[e] + 1e-5f);
            featbn[b * 2048 + e] = (val - mm[e]) * scv + bb[e];
        }
    }
}

// ---- head stage 1 (vectorized): bn(feat)@W1+b1 -> bn2 -> lrelu -------------
__global__ __launch_bounds__(256) void k_head1(
    const float* __restrict__ featbn,
    const float* __restrict__ W1, const float* __restrict__ b1,
    const float* __restrict__ g2, const float* __restrict__ bb2,
    const float* __restrict__ mm2, const float* __restrict__ vv2,
    float* __restrict__ h2ws)
{
    __shared__ float featL[2048];
    __shared__ float part[32][32];
    int tid = threadIdx.x, blk = blockIdx.x;
    int b = blk >> 4, cc = blk & 15;
    {
        const float4* src = reinterpret_cast<const float4*>(featbn + b * 2048);
        float4* dst = reinterpret_cast<float4*>(featL);
        for (int i = tid; i < 512; i += 256) dst[i] = src[i];
    }
    __syncthreads();
    int ks = tid >> 3, cg = tid & 7;
    int col0 = cc * 32 + cg * 4;
    float4 acc = {0.f, 0.f, 0.f, 0.f};
    const float* fl = featL + ks * 64;
    for (int c = 0; c < 64; ++c) {
        int k = ks * 64 + c;
        float4 wv = *reinterpret_cast<const float4*>(W1 + (size_t)k * 512 + col0);
        float fv = fl[c];
        acc.x += fv * wv.x; acc.y += fv * wv.y;
        acc.z += fv * wv.z; acc.w += fv * wv.w;
    }
    part[ks][cg * 4 + 0] = acc.x;
    part[ks][cg * 4 + 1] = acc.y;
    part[ks][cg * 4 + 2] = acc.z;
    part[ks][cg * 4 + 3] = acc.w;
    __syncthreads();
    if (tid < 32) {
        int colw = cc * 32 + tid;
        float s = b1[colw];
        for (int k2 = 0; k2 < 32; ++k2) s += part[k2][tid];
        float scv = g2[colw] * rsqrtf(vv2[colw] + 1e-5f);
        float val = (s - mm2[colw]) * scv + bb2[colw];
        h2ws[b * 512 + colw] = lrelu(val);
    }
}

// ---- tail: h2 @ W2 + b2, softmax -> dout[0:160]; MMD + CE -> dout[160] -----
__global__ __launch_bounds__(256) void k_tail(
    const float* __restrict__ h2ws,
    const float* __restrict__ W2, const float* __restrict__ b2,
    const float* __restrict__ sa, const float* __restrict__ ta,
    const float* __restrict__ sb, const float* __restrict__ tb,
    const int* __restrict__ sy, float* __restrict__ dout)
{
    __shared__ float h2L[8192];
    __shared__ float lgL[160], ypL[160];
    __shared__ float sA[8], sB[8];
    int tid = threadIdx.x;
    for (int i = tid; i < 8192; i += 256) h2L[i] = h2ws[i];
    if (tid < 8) { sA[tid] = 0.f; sB[tid] = 0.f; }
    __syncthreads();
    if (tid < 160) {
        int b = tid / 10, j = tid - b * 10;
        float a = b2[j];
        const float* h = h2L + b * 512;
        for (int c = 0; c < 512; ++c) a += h[c] * W2[c * 10 + j];
        lgL[tid] = a;
    }
    __syncthreads();
    if (tid < 16) {
        int b = tid;
        float mx = lgL[b * 10];
        for (int j = 1; j < 10; ++j) mx = fmaxf(mx, lgL[b * 10 + j]);
        float sum = 0.f, ex[10];
        for (int j = 0; j < 10; ++j) { ex[j] = expf(lgL[b * 10 + j] - mx); sum += ex[j]; }
        for (int j = 0; j < 10; ++j) {
            float p = ex[j] / sum;
            ypL[b * 10 + j] = p;
            dout[b * 10 + j] = p;
        }
    }
    __syncthreads();
    if (tid < 128) {
        int f = tid >> 4, s = tid & 15;
        float d = 0.f;
        for (int b = 0; b < 16; ++b) d += sa[f * 256 + b * 16 + s] - ta[f * 256 + b * 16 + s];
        d *= (1.f / 16.f);
        atomicAdd(&sA[f], d * d);
    }
    for (int e = tid; e < 1024; e += 256) {
        int i = e >> 7, f = (e >> 4) & 7, s = e & 15;
        float d = 0.f;
        int base = ((i * 8 + f) * 16) * 16 + s;
        for (int b = 0; b < 16; ++b) d += sb[base + b * 16] - tb[base + b * 16];
        d *= (1.f / 16.f);
        atomicAdd(&sB[i], d * d);
    }
    __syncthreads();
    if (tid == 0) {
        float la = 0.f, lb = 0.f;
        for (int f = 0; f < 8; ++f) la += sqrtf(sA[f]);
        for (int i = 0; i < 8; ++i) lb += sqrtf(sB[i]);
        la *= 0.1f / 8.f;
        lb *= 0.1f / 8.f;
        float ce = 0.f;
        for (int b = 0; b < 16; ++b) {
            const float* y = ypL + b * 10;
            float mx = y[0];
            for (int j = 1; j < 10; ++j) mx = fmaxf(mx, y[j]);
            float sum = 0.f;
            for (int j = 0; j < 10; ++j) sum += expf(y[j] - mx);
            float lse = mx + logf(sum);
            ce += lse - y[sy[b]];
        }
        ce *= (1.f / 16.f);
        dout[160] = ce + la + lb;
    }
}

extern "C" void kernel_launch(void* const* d_in, const int* in_sizes, int n_in,
                              void* d_out, int out_size, void* d_ws, size_t ws_size,
                              hipStream_t stream) {
    (void)in_sizes; (void)n_in; (void)out_size; (void)ws_size;
    const float* src_x = (const float*)d_in[0];
    const int*   src_y = (const int*)d_in[1];
    const float* tgt_x = (const float*)d_in[2];
    const float *cw1 = (const float*)d_in[3], *bn1g = (const float*)d_in[4],
                *bn1b = (const float*)d_in[5], *bn1m = (const float*)d_in[6],
                *bn1v = (const float*)d_in[7];
    const float *cw2 = (const float*)d_in[8], *bn2g = (const float*)d_in[9],
                *bn2b = (const float*)d_in[10], *bn2m = (const float*)d_in[11],
                *bn2v = (const float*)d_in[12];
    const float *cw3 = (const float*)d_in[13], *bn3g = (const float*)d_in[14],
                *bn3b = (const float*)d_in[15], *bn3m = (const float*)d_in[16],
                *bn3v = (const float*)d_in[17];
    const float *Wq = (const float*)d_in[18], *bq = (const float*)d_in[19],
                *Wk = (const float*)d_in[20], *bk = (const float*)d_in[21],
                *Wv = (const float*)d_in[22], *bv = (const float*)d_in[23];
    const float *bc1g = (const float*)d_in[24], *bc1b = (const float*)d_in[25],
                *bc1m = (const float*)d_in[26], *bc1v = (const float*)d_in[27];
    const float *W1 = (const float*)d_in[28], *b1 = (const float*)d_in[29];
    const float *bc2g = (const float*)d_in[30], *bc2b = (const float*)d_in[31],
                *bc2m = (const float*)d_in[32], *bc2v = (const float*)d_in[33];
    const float *W2 = (const float*)d_in[34], *b2 = (const float*)d_in[35];

    float* ws = (float*)d_ws;
    size_t o = 0;
    float* rep    = ws + o; o += (size_t)2 * 262144;   // [pass][f,n,h]
    float* Zn     = ws + o; o += (size_t)2 * 16384;
    float* rninv  = ws + o; o += (size_t)2 * 2048;
    float* ia     = ws + o; o += (size_t)2 * 2048;
    float* ib     = ws + o; o += (size_t)2 * 16384;
    float* featbn = ws + o; o += (size_t)16 * 2048;
    float* h2ws   = ws + o; o += (size_t)16 * 512;
    u16* wpk2 = (u16*)(ws + o); o += 65536;            // 131072 u16
    u16* wpk3 = (u16*)(ws + o); o += 262144;           // 524288 u16
    u16* wqkv = (u16*)(ws + o); o += 24576;            // 49152 u16

    k_wprep<<<688, 256, 0, stream>>>(cw2, cw3, Wq, Wk, Wv, wpk2, wpk3, wqkv);
    k_cnn<<<4096, 256, 0, stream>>>(src_x, tgt_x,
        cw1, bn1g, bn1b, bn1m, bn1v,
        bn2g, bn2b, bn2m, bn2v,
        bn3g, bn3b, bn3m, bn3v,
        wpk2, wpk3, rep);
    k_attn1<<<256, 256, 0, stream>>>(rep, wqkv, bq, bk, bv, Zn, rninv, ia);
    k_attn2<<<256, 256, 0, stream>>>(rep, Zn, rninv, ib, bc1g, bc1b, bc1m, bc1v, featbn);
    k_head1<<<256, 256, 0, stream>>>(featbn, W1, b1, bc2g, bc2b, bc2m, bc2v, h2ws);
    k_tail<<<1, 256, 0, stream>>>(h2ws, W2, b2, ia, ia + 2048, ib, ib + 16384,
                                  src_y, (float*)d_out);
}